// Round 8
// baseline (766.813 us; speedup 1.0000x reference)
//
#include <hip/hip_runtime.h>

typedef __attribute__((ext_vector_type(8))) short short8;
typedef __attribute__((ext_vector_type(4))) float f32x4;

constexpr int L = 1024, C = 256, F = 256;
constexpr int NIMG = 256;          // B*M
constexpr int LOUT = 1022;         // L - K + 1
constexpr long MAXROW = (long)NIMG * L - 1;

__device__ inline unsigned short f2bf(float f) {
  union { float f; unsigned u; } v; v.f = f;
  return (unsigned short)((v.u + 0x7FFFu + ((v.u >> 16) & 1u)) >> 16);  // RNE
}

__device__ inline void g2l16(const unsigned short* g, unsigned short* l) {
  __builtin_amdgcn_global_load_lds(
      (const __attribute__((address_space(1))) unsigned int*)g,
      (__attribute__((address_space(3))) unsigned int*)l, 16, 0, 0);
}

// Pre-pass: W (3,256,256) fp32 -> Wt bf16, LINEAR layout [tile(slab*3+k)][f(256)][kp(32)]
__global__ void wprep(const float* __restrict__ W, unsigned short* __restrict__ Wt) {
  int tid = blockIdx.x * 256 + threadIdx.x;       // exactly 768*256 threads
  int kc = tid >> 8, f = tid & 255;               // coalesced read of W[tid]
  int k = kc >> 8, c = kc & 255;
  int slab = c >> 5, kp = c & 31;
  Wt[(size_t)(((slab * 3 + k) * 256 + f) * 32 + kp)] = f2bf(W[tid]);
}

// R8: A never touches LDS. The 16x16x32 A-fragment is per-lane contiguous in
// global memory (lane (quad,lr) needs x[row=mi*16+lr+k][c=cb+quad*8..+8] =
// 32 B), so each lane loads 2xfloat4 and packs bf16 in registers. Taps k=1,2
// re-read shifted rows from L1 (66-row tile is L1-resident). This deletes
// write_A / av-FIFO / lgkm publishes / As, halves LDS reads, and shrinks the
// barrier domain to 4 waves. Only LDS: B tri-buffer (DMA, dist-2, exact
// vmcnt(0) at region tops since A loads are compiler-tracked and consumed
// before each pack). 48.5 KB LDS + ~90 VGPR + 64 AGPR -> 3 blocks/CU.
__global__ __launch_bounds__(256) void conv_mfma(
    const float* __restrict__ x, const unsigned short* __restrict__ Wt,
    const float* __restrict__ bias, float* __restrict__ y)
{
  __shared__ __align__(16) unsigned short Bs[3][512 * 16];  // 3 x 16384 B

  const int bid = blockIdx.x;       // 4096 blocks
  const int lt  = bid & 15;         // 16 l-tiles of 64 rows over Lout=1022
  const int img = bid >> 4;         // 256 images
  const int l0  = lt * 64;

  const int tid  = threadIdx.x;
  const int lane = tid & 63;
  const int wc   = tid >> 6;        // 4 waves = 4 F quadrants; wave tile 64x64
  const int lr   = lane & 15;
  const int quad = lane >> 4;

  f32x4 acc[4][4] = {};

  // Per-lane clamped byte offsets for the 12 A rows (mi*16 + lr + k).
  // Clamped rows feed only masked outputs (lrow >= LOUT). Max offset
  // 262143*1024 + 96+... < 2^31 -> fits int.
  const long gb = (long)img * L + l0;
  int roff[4][3];
#pragma unroll
  for (int mi = 0; mi < 4; ++mi)
#pragma unroll
    for (int k = 0; k < 3; ++k) {
      long g = gb + mi * 16 + lr + k;
      if (g > MAXROW) g = MAXROW;
      roff[mi][k] = (int)(g * (C * 4)) + quad * 32;
    }
  const char* xb = (const char*)x;

  auto pack8 = [&](float4 a, float4 b) {
    short8 r;
    r[0] = (short)f2bf(a.x); r[1] = (short)f2bf(a.y);
    r[2] = (short)f2bf(a.z); r[3] = (short)f2bf(a.w);
    r[4] = (short)f2bf(b.x); r[5] = (short)f2bf(b.y);
    r[6] = (short)f2bf(b.z); r[7] = (short)f2bf(b.w);
    return r;
  };

  auto ldA = [&](int mi, int k, int slab) {   // 32 B contiguous global -> bf16x8
    const float4* p = (const float4*)(xb + (size_t)(unsigned)roff[mi][k] + slab * 128);
    return pack8(p[0], p[1]);
  };

  auto stage_B = [&](int tile, int bb) {      // 16 KB contiguous, 4 g2l16/thread
    const unsigned short* bsrc = Wt + (size_t)tile * 8192;
#pragma unroll
    for (int j = 0; j < 4; ++j)
      g2l16(bsrc + (size_t)(tid + j * 256) * 8, Bs[bb] + (size_t)(tid + j * 256) * 8);
  };

  auto tap = [&](int kbuf, int k, int slab) {
    short8 af[4], bf[4];
#pragma unroll
    for (int mi = 0; mi < 4; ++mi) af[mi] = ldA(mi, k, slab);
#pragma unroll
    for (int ni = 0; ni < 4; ++ni)
      bf[ni] = *(const short8*)(Bs[kbuf] + (size_t)(wc * 64 + ni * 16 + lr) * 32 + quad * 8);
    __builtin_amdgcn_s_setprio(1);
#pragma unroll
    for (int mi = 0; mi < 4; ++mi)
#pragma unroll
      for (int ni = 0; ni < 4; ++ni)
        acc[mi][ni] = __builtin_amdgcn_mfma_f32_16x16x32_bf16(
            af[mi], bf[ni], acc[mi][ni], 0, 0, 0);
    __builtin_amdgcn_s_setprio(0);
  };

  // ---- prologue: tiles 0,1 in flight (8 DMAs)
  stage_B(0, 0);
  stage_B(1, 1);

  for (int s = 0; s < 8; ++s) {
    // ======== R0(s): taps 0,1 ========
    // Outstanding VMEM here = R1(s-1)'s 8 stage-DMAs (or prologue's 8):
    // A-register loads were all consumed by packs before this point, so
    // vmcnt(0) is an exact drain of the staging only.
    asm volatile("s_waitcnt vmcnt(0)" ::: "memory");
    __builtin_amdgcn_s_barrier();
    __builtin_amdgcn_sched_barrier(0);

    stage_B(3 * s + 2, 2);          // Bs[2] consumed in R1(s); 1-region cover
    tap(0, 0, s);                   // tile 3s   in Bs[0]
    tap(1, 1, s);                   // tile 3s+1 in Bs[1]

    // ======== R1(s): tap 2 ========
    asm volatile("s_waitcnt vmcnt(0)" ::: "memory");  // drain tile 3s+2 DMA
    __builtin_amdgcn_s_barrier();
    __builtin_amdgcn_sched_barrier(0);

    if (s < 7) {                    // Bs[0]/Bs[1] fully consumed in R0(s)
      stage_B(3 * s + 3, 0);
      stage_B(3 * s + 4, 1);
    }
    tap(2, 2, s);                   // tile 3s+2 in Bs[2]
  }

  // Epilogue: C/D layout col=lane&15, row=quad*4+reg (m89/m91-verified)
  float bv[4];
#pragma unroll
  for (int ni = 0; ni < 4; ++ni)
    bv[ni] = bias[wc * 64 + ni * 16 + lr];

#pragma unroll
  for (int mi = 0; mi < 4; ++mi) {
#pragma unroll
    for (int r = 0; r < 4; ++r) {
      const int lrow = l0 + mi * 16 + quad * 4 + r;
      if (lrow < LOUT) {
        float* yp = y + ((size_t)img * LOUT + lrow) * F + wc * 64 + lr;
#pragma unroll
        for (int ni = 0; ni < 4; ++ni)
          yp[ni * 16] = acc[mi][ni][r] + bv[ni];
      }
    }
  }
}

extern "C" void kernel_launch(void* const* d_in, const int* in_sizes, int n_in,
                              void* d_out, int out_size, void* d_ws, size_t ws_size,
                              hipStream_t stream) {
  const float* x = (const float*)d_in[0];   // (8,32,1024,256) fp32
  const float* W = (const float*)d_in[1];   // (3,256,256) fp32
  const float* b = (const float*)d_in[2];   // (256,) fp32
  float* y = (float*)d_out;                 // (8,32,1022,256) fp32
  unsigned short* Wt = (unsigned short*)d_ws;  // 3*256*256*2 = 393,216 B

  wprep<<<768, 256, 0, stream>>>(W, Wt);
  conv_mfma<<<NIMG * 16, 256, 0, stream>>>(x, Wt, b, y);
}

// Round 9
// 490.504 us; speedup vs baseline: 1.5633x; 1.5633x over previous
//
#include <hip/hip_runtime.h>

typedef __attribute__((ext_vector_type(8))) short short8;
typedef __attribute__((ext_vector_type(4))) float f32x4;

constexpr int L = 1024, C = 256, F = 256;
constexpr int NIMG = 256;          // B*M
constexpr int LOUT = 1022;         // L - K + 1
constexpr long MAXROW = (long)NIMG * L - 1;

__device__ inline unsigned short f2bf(float f) {
  union { float f; unsigned u; } v; v.f = f;
  return (unsigned short)((v.u + 0x7FFFu + ((v.u >> 16) & 1u)) >> 16);  // RNE
}

__device__ inline void g2l16(const unsigned short* g, unsigned short* l) {
  __builtin_amdgcn_global_load_lds(
      (const __attribute__((address_space(1))) unsigned int*)g,
      (__attribute__((address_space(3))) unsigned int*)l, 16, 0, 0);
}

// Pre-pass: W (3,256,256) fp32 -> Wt bf16, LINEAR layout [tile(slab*3+k)][f(256)][kp(32)]
__global__ void wprep(const float* __restrict__ W, unsigned short* __restrict__ Wt) {
  int tid = blockIdx.x * 256 + threadIdx.x;       // exactly 768*256 threads
  int kc = tid >> 8, f = tid & 255;               // coalesced read of W[tid]
  int k = kc >> 8, c = kc & 255;
  int slab = c >> 5, kp = c & 31;
  Wt[(size_t)(((slab * 3 + k) * 256 + f) * 32 + kp)] = f2bf(W[tid]);
}

// R9: m201-faithful port. 512 thr / 8 waves, block 256Lx256F, wave 128x64
// (acc[8][4] = 128 AGPR), 2 waves/SIMD, 1 block/CU (82 KB LDS). Per tap
// (K=32): vmcnt(N)+barrier at tap top only; 2 phases x {ds_reads -> barrier
// -> lgkm0 -> 16 MFMA} (m201's 16-MFMA-per-phase grain, proven at 2 w/SIMD).
// Tri-buffered Bs dist-2; av issued tap0, packed tap2-P1 (compiler drains av,
// resetting the DMA FIFO each slab -- waits below derived from that).
__global__ __launch_bounds__(512, 2) void conv_mfma(
    const float* __restrict__ x, const unsigned short* __restrict__ Wt,
    const float* __restrict__ bias, float* __restrict__ y)
{
  __shared__ __align__(16) unsigned short As[2][1032 * 8];  // 2 x 16512 B (258 rows x 32 bf16)
  __shared__ __align__(16) unsigned short Bs[3][512 * 16];  // 3 x 16384 B (256 f x 32 bf16)

  const int bid = blockIdx.x;       // 1024 blocks
  const int lt  = bid & 3;          // 4 l-tiles of 256 rows over Lout=1022
  const int img = bid >> 2;         // 256 images
  const int l0  = lt * 256;

  const int tid  = threadIdx.x;
  const int lane = tid & 63;
  const int wv   = tid >> 6;        // 8 waves: 2(M) x 4(F); wave tile 128 x 64
  const int wr   = wv >> 2;
  const int wc   = wv & 3;
  const int lr   = lane & 15;
  const int quad = lane >> 4;

  f32x4 acc[8][4] = {};             // 128 AGPR
  float4 av[2][2];                  // A chunks tid, tid+512
  float4 avt[2];                    // tail chunks 1024..1031 (tid < 8)

  const long gb = (long)img * L + l0;

  auto issue_A = [&](int slab) {    // global -> regs, rows 0..257 of slab (fp32)
    const int cb = slab * 32;
    long g0 = gb + (tid >> 2);        if (g0 > MAXROW) g0 = MAXROW;  // clamped rows
    long g1 = gb + 128 + (tid >> 2);  if (g1 > MAXROW) g1 = MAXROW;  // feed only
    const float* p0 = x + g0 * C + cb + (tid & 3) * 8;               // masked outputs
    const float* p1 = x + g1 * C + cb + (tid & 3) * 8;
    av[0][0] = *(const float4*)p0; av[0][1] = *(const float4*)(p0 + 4);
    av[1][0] = *(const float4*)p1; av[1][1] = *(const float4*)(p1 + 4);
    if (tid < 8) {
      long g2 = gb + 256 + (tid >> 2); if (g2 > MAXROW) g2 = MAXROW;
      const float* p2 = x + g2 * C + cb + (tid & 3) * 8;
      avt[0] = *(const float4*)p2; avt[1] = *(const float4*)(p2 + 4);
    }
  };

  auto pack8 = [&](float4 a, float4 b) {
    short8 r;
    r[0] = (short)f2bf(a.x); r[1] = (short)f2bf(a.y);
    r[2] = (short)f2bf(a.z); r[3] = (short)f2bf(a.w);
    r[4] = (short)f2bf(b.x); r[5] = (short)f2bf(b.y);
    r[6] = (short)f2bf(b.z); r[7] = (short)f2bf(b.w);
    return r;
  };

  auto write_A = [&](int p) {       // 1032 chunks of 16 B, contiguous -> balanced
    *(short8*)(As[p] + (size_t)tid * 8)         = pack8(av[0][0], av[0][1]);
    *(short8*)(As[p] + (size_t)(tid + 512) * 8) = pack8(av[1][0], av[1][1]);
    if (tid < 8)
      *(short8*)(As[p] + (size_t)(1024 + tid) * 8) = pack8(avt[0], avt[1]);
  };

  auto stage_B = [&](int tile, int bb) {  // 16 KB contiguous, 2 g2l16/thread
    const unsigned short* bsrc = Wt + (size_t)tile * 8192;
    g2l16(bsrc + (size_t)tid * 8,         Bs[bb] + (size_t)tid * 8);
    g2l16(bsrc + (size_t)(tid + 512) * 8, Bs[bb] + (size_t)(tid + 512) * 8);
  };

  auto read_af = [&](int p, int k, int mi) {   // row = wr*128 + mi*16 + lr + k
    return *(const short8*)(As[p] + (size_t)((wr * 128 + mi * 16 + lr + k) * 4 + quad) * 8);
  };
  auto read_bf = [&](int buf, int ni) {
    return *(const short8*)(Bs[buf] + (size_t)((wc * 64 + ni * 16 + lr) * 4 + quad) * 8);
  };

#define BAR   __builtin_amdgcn_s_barrier()
#define SBAR  __builtin_amdgcn_sched_barrier(0)
#define LGKM0 asm volatile("s_waitcnt lgkmcnt(0)" ::: "memory")
#define MFMA_HALF(H)                                                          \
  do {                                                                        \
    __builtin_amdgcn_s_setprio(1);                                            \
    _Pragma("unroll")                                                         \
    for (int mi = 0; mi < 4; ++mi)                                            \
      _Pragma("unroll")                                                       \
      for (int ni = 0; ni < 4; ++ni)                                          \
        acc[(H) * 4 + mi][ni] = __builtin_amdgcn_mfma_f32_16x16x32_bf16(      \
            af[mi], bf[ni], acc[(H) * 4 + mi][ni], 0, 0, 0);                  \
    __builtin_amdgcn_s_setprio(0);                                            \
  } while (0)

  // One tap = tap-boundary (vmcnt VM + barrier) then 2 phases of 16 MFMA.
  // STG: tile to stage (-1 = none, buf = (TAU+2)%3); DOA: issue_A(s+1);
  // DOWA: write_A at P1 (publish via post-barrier lgkm0 before next tap-top).
#define TAP(S, TAU, VM, STG, DOA, DOWA)                                       \
  do {                                                                        \
    asm volatile("s_waitcnt vmcnt(" #VM ")" ::: "memory");                    \
    BAR; SBAR;                                                                \
    short8 af[4], bf[4];                                                      \
    if ((STG) >= 0) stage_B((STG), ((TAU) + 2) % 3);                          \
    if (DOA) issue_A((S) + 1);                                                \
    _Pragma("unroll")                                                         \
    for (int mi = 0; mi < 4; ++mi) af[mi] = read_af((S) & 1, (TAU), mi);      \
    _Pragma("unroll")                                                         \
    for (int ni = 0; ni < 4; ++ni) bf[ni] = read_bf((TAU), ni);               \
    SBAR; BAR; LGKM0; SBAR;                                                   \
    MFMA_HALF(0);                                                             \
    BAR;                                                                      \
    _Pragma("unroll")                                                         \
    for (int mi = 0; mi < 4; ++mi) af[mi] = read_af((S) & 1, (TAU), 4 + mi);  \
    if (DOWA) write_A(((S) & 1) ^ 1);                                         \
    SBAR; BAR; LGKM0; SBAR;                                                   \
    MFMA_HALF(1);                                                             \
  } while (0)

  // ---- prologue: tiles 0,1 + av(0) in flight; write_A(0) (compiler drains
  // av -> whole FIFO drained, cold start); publish writes before first barrier.
  stage_B(0, 0);
  stage_B(1, 1);
  issue_A(0);
  write_A(0);
  LGKM0;

  for (int s = 0; s < 7; ++s) {
    // FIFO at tap tops (invariant: slab entry = [3s(2), 3s+1(2)]):
    //  tau0: [3s,3s+1] need 3s        -> vmcnt(2); then +stage(3s+2)+av
    //  tau1: [3s+1,3s+2,av] need 3s+1 -> vmcnt(4); then +stage(3s+3)
    //  tau2: [3s+2,av,3s+3] need 3s+2 -> vmcnt(4); then +stage(3s+4);
    //        write_A drains av -> exit [3s+3,3s+4] = next slab's invariant.
    //  (wave0's +2 avt loads sit adjacent to av: same counts are stricter.)
    TAP(s, 0, 2, 3 * s + 2, 1, 0);
    TAP(s, 1, 4, 3 * s + 3, 0, 0);
    TAP(s, 2, 4, 3 * s + 4, 0, 1);
  }
  // ---- tail slab s=7: entry FIFO [21,22]; no av, no write_A.
  TAP(7, 0, 2, 23, 0, 0);          // need 21; stage 23 -> [22,23]
  TAP(7, 1, 2, -1, 0, 0);          // need 22 -> vmcnt(2) leaves [23]
  TAP(7, 2, 0, -1, 0, 0);          // need 23 -> vmcnt(0)

  // Epilogue: C/D layout col=lane&15, row=quad*4+reg (m89/m91-verified)
  float bv[4];
#pragma unroll
  for (int ni = 0; ni < 4; ++ni)
    bv[ni] = bias[wc * 64 + ni * 16 + lr];

#pragma unroll
  for (int mi = 0; mi < 8; ++mi) {
#pragma unroll
    for (int r = 0; r < 4; ++r) {
      const int lrow = l0 + wr * 128 + mi * 16 + quad * 4 + r;
      if (lrow < LOUT) {
        float* yp = y + ((size_t)img * LOUT + lrow) * F + wc * 64 + lr;
#pragma unroll
        for (int ni = 0; ni < 4; ++ni)
          yp[ni * 16] = acc[mi][ni][r] + bv[ni];
      }
    }
  }
#undef TAP
#undef MFMA_HALF
#undef BAR
#undef SBAR
#undef LGKM0
}

extern "C" void kernel_launch(void* const* d_in, const int* in_sizes, int n_in,
                              void* d_out, int out_size, void* d_ws, size_t ws_size,
                              hipStream_t stream) {
  const float* x = (const float*)d_in[0];   // (8,32,1024,256) fp32
  const float* W = (const float*)d_in[1];   // (3,256,256) fp32
  const float* b = (const float*)d_in[2];   // (256,) fp32
  float* y = (float*)d_out;                 // (8,32,1022,256) fp32
  unsigned short* Wt = (unsigned short*)d_ws;  // 3*256*256*2 = 393,216 B

  wprep<<<768, 256, 0, stream>>>(W, Wt);
  conv_mfma<<<NIMG * 4, 512, 0, stream>>>(x, Wt, b, y);
}

// Round 10
// 470.731 us; speedup vs baseline: 1.6290x; 1.0420x over previous
//
#include <hip/hip_runtime.h>

typedef __attribute__((ext_vector_type(8))) short short8;
typedef __attribute__((ext_vector_type(4))) float f32x4;

constexpr int L = 1024, C = 256, F = 256;
constexpr int NIMG = 256;          // B*M
constexpr int LOUT = 1022;         // L - K + 1
constexpr long MAXROW = (long)NIMG * L - 1;

__device__ inline unsigned short f2bf(float f) {
  union { float f; unsigned u; } v; v.f = f;
  return (unsigned short)((v.u + 0x7FFFu + ((v.u >> 16) & 1u)) >> 16);  // RNE
}

__device__ inline void g2l16(const unsigned short* g, unsigned short* l) {
  __builtin_amdgcn_global_load_lds(
      (const __attribute__((address_space(1))) unsigned int*)g,
      (__attribute__((address_space(3))) unsigned int*)l, 16, 0, 0);
}

// Pre-pass: W (3,256,256) fp32 -> Wt bf16, layout [tile(slab*3+k)][f(256)][kp(32)]
__global__ void wprep(const float* __restrict__ W, unsigned short* __restrict__ Wt) {
  int tid = blockIdx.x * 256 + threadIdx.x;       // exactly 768*256 threads
  int kc = tid >> 8, f = tid & 255;               // coalesced read of W[tid]
  int k = kc >> 8, c = kc & 255;
  int slab = c >> 5, kp = c & 31;
  Wt[(size_t)(((slab * 3 + k) * 256 + f) * 32 + kp)] = f2bf(W[tid]);
}

// R10 = R5 (163 us anchor) + anti-phase entry shift. Timeline model (fits the
// measured 6.1k cyc/region-pair): the 2 resident blocks run identical
// read-burst -> MFMA-burst rhythms IN PHASE, so each pipe idles ~50%.
// Odd-parity blocks sleep ~3k cyc once at entry (after prologue DMA issue) to
// land in the anti-phase basin; setprio around MFMA stabilizes it. Parity
// hash ((bid>>8)^bid)&1 flips for co-resident pairs under both Delta=256
// (XCD/CU round-robin) and Delta=1 dispatch models. No other change.
__global__ __launch_bounds__(512, 4) void conv_mfma(
    const float* __restrict__ x, const unsigned short* __restrict__ Wt,
    const float* __restrict__ bias, float* __restrict__ y)
{
  __shared__ __align__(16) unsigned short As[2][520 * 8];   // 2 x 8320 B (130 rows x 32 bf16)
  __shared__ __align__(16) unsigned short Bs[3][512 * 16];  // 3 x 16384 B (256 f x 32 bf16)

  const int bid = blockIdx.x;       // 2048 blocks
  const int mt  = bid & 7;          // 8 m-tiles of 128 rows over Lout=1022
  const int img = bid >> 3;         // 256 images
  const int l0  = mt * 128;

  const int tid  = threadIdx.x;
  const int lane = tid & 63;
  const int wv   = tid >> 6;        // 8 waves: 2(M) x 4(F); wave tile 64 x 64
  const int wr   = wv >> 2;
  const int wc   = wv & 3;
  const int lr   = lane & 15;
  const int quad = lane >> 4;

  f32x4 acc[4][4] = {};
  float4 av[2];                     // A chunk tid (2 dwordx4 loads/wave)
  float4 avt[2];                    // tail chunks 512..519 (wave 0 only, +2 loads)

  const long gb = (long)img * L + l0;

  auto issue_A = [&](int slab) {    // global -> regs, rows 0..129 of slab (fp32)
    const int cb = slab * 32;
    long g0 = gb + (tid >> 2); if (g0 > MAXROW) g0 = MAXROW;   // clamped rows feed
    const float* p0 = x + g0 * C + cb + (tid & 3) * 8;         // only masked outputs
    av[0] = *(const float4*)p0; av[1] = *(const float4*)(p0 + 4);
    if (tid < 8) {
      long g2 = gb + 128 + (tid >> 2); if (g2 > MAXROW) g2 = MAXROW;
      const float* p2 = x + g2 * C + cb + (tid & 3) * 8;
      avt[0] = *(const float4*)p2; avt[1] = *(const float4*)(p2 + 4);
    }
  };

  auto pack8 = [&](float4 a, float4 b) {
    short8 r;
    r[0] = (short)f2bf(a.x); r[1] = (short)f2bf(a.y);
    r[2] = (short)f2bf(a.z); r[3] = (short)f2bf(a.w);
    r[4] = (short)f2bf(b.x); r[5] = (short)f2bf(b.y);
    r[6] = (short)f2bf(b.z); r[7] = (short)f2bf(b.w);
    return r;
  };

  auto write_A = [&](int ab2) {     // 520 chunks of 16 B, contiguous -> balanced
    *(short8*)(As[ab2] + (size_t)tid * 8) = pack8(av[0], av[1]);
    if (tid < 8)
      *(short8*)(As[ab2] + (size_t)(512 + tid) * 8) = pack8(avt[0], avt[1]);
  };

  auto stage_B = [&](int tile, int bb) {  // 16 KB contiguous, 2 g2l16/thread
    const unsigned short* bsrc = Wt + (size_t)tile * 8192;
    g2l16(bsrc + (size_t)tid * 8,         Bs[bb] + (size_t)tid * 8);
    g2l16(bsrc + (size_t)(tid + 512) * 8, Bs[bb] + (size_t)(tid + 512) * 8);
  };

  auto read_af = [&](int ab2, int k, int mi) {
    return *(const short8*)(As[ab2] + (wr * 64 + mi * 16 + lr + k) * 32 + quad * 8);
  };
  auto read_bf = [&](int kbuf, int ni) {
    return *(const short8*)(Bs[kbuf] + (wc * 64 + ni * 16 + lr) * 32 + quad * 8);
  };

#define BAR  __builtin_amdgcn_s_barrier()
#define SBAR __builtin_amdgcn_sched_barrier(0)

  // ---- prologue: B0, B1, av(0) issued; write_A drains av (compiler wait);
  // R0(0)'s top wait (vmcnt0+lgkm0) finishes the drain before the barrier.
  stage_B(0, 0);
  stage_B(1, 1);
  issue_A(0);
  write_A(0);

  // Anti-phase shift: odd-parity blocks delay ~3k cyc (half a region-pair
  // period) AFTER prologue DMAs are in flight. Wave-uniform branch.
  if (((bid >> 8) ^ bid) & 1) {
    asm volatile("s_sleep 48" ::: "memory");   // ~48*64 = 3072 clocks
  }

  for (int s = 0; s < 8; ++s) {
    const int ab = s & 1;

    // ======== R0(s): taps 0,1 ========
    // top: pending = R1(s-1)'s 4 stage loads (or prologue) -> drain all;
    // lgkm0 publishes write_A(ab) from R1(s-1).
    asm volatile("s_waitcnt vmcnt(0) lgkmcnt(0)" ::: "memory");
    BAR; SBAR;

    stage_B(3 * s + 2, 2);          // Bs[2] not read in R0; consumed in R1(s)
    if (s < 7) issue_A(s + 1);      // av after stage (FIFO: R1-top keeps av)

#pragma unroll
    for (int tap = 0; tap < 2; ++tap) {
      short8 af[4], bf[4];
#pragma unroll
      for (int mi = 0; mi < 4; ++mi) af[mi] = read_af(ab, tap, mi);
#pragma unroll
      for (int ni = 0; ni < 4; ++ni) bf[ni] = read_bf(tap, ni);  // tile 3s+tap
      __builtin_amdgcn_s_setprio(1);
#pragma unroll
      for (int mi = 0; mi < 4; ++mi)
#pragma unroll
        for (int ni = 0; ni < 4; ++ni)
          acc[mi][ni] = __builtin_amdgcn_mfma_f32_16x16x32_bf16(
              af[mi], bf[ni], acc[mi][ni], 0, 0, 0);
      __builtin_amdgcn_s_setprio(0);
    }

    // ======== R1(s): tap 2 ========
    // top: pending (s<7) = [tile 3s+2 (2), av (2)] -> vmcnt(2) drains the tile,
    // keeps av in flight (wave0's avt: same count is stricter, safe).
    // s==7: no av -> vmcnt(0).
    if (s < 7) asm volatile("s_waitcnt vmcnt(2)" ::: "memory");
    else       asm volatile("s_waitcnt vmcnt(0)" ::: "memory");
    BAR; SBAR;

    if (s < 7) {                    // Bs[0]/Bs[1] fully consumed in R0(s)
      stage_B(3 * s + 3, 0);
      stage_B(3 * s + 4, 1);
    }

    {
      short8 af[4], bf[4];
#pragma unroll
      for (int mi = 0; mi < 4; ++mi) af[mi] = read_af(ab, 2, mi);
#pragma unroll
      for (int ni = 0; ni < 4; ++ni) bf[ni] = read_bf(2, ni);    // tile 3s+2
      __builtin_amdgcn_s_setprio(1);
#pragma unroll
      for (int mi = 0; mi < 4; ++mi)
#pragma unroll
        for (int ni = 0; ni < 4; ++ni)
          acc[mi][ni] = __builtin_amdgcn_mfma_f32_16x16x32_bf16(
              af[mi], bf[ni], acc[mi][ni], 0, 0, 0);
      __builtin_amdgcn_s_setprio(0);
    }

    if (s < 7) write_A(ab ^ 1);     // after MFMAs: implicit av-wait off the
                                    // critical path; published at next R0-top
  }

  // Epilogue: C/D layout col=lane&15, row=quad*4+reg (m89/m91-verified)
  float bv[4];
#pragma unroll
  for (int ni = 0; ni < 4; ++ni)
    bv[ni] = bias[wc * 64 + ni * 16 + lr];

#pragma unroll
  for (int mi = 0; mi < 4; ++mi) {
#pragma unroll
    for (int r = 0; r < 4; ++r) {
      const int lrow = l0 + wr * 64 + mi * 16 + quad * 4 + r;
      if (lrow < LOUT) {
        float* yp = y + ((size_t)img * LOUT + lrow) * F + wc * 64 + lr;
#pragma unroll
        for (int ni = 0; ni < 4; ++ni)
          yp[ni * 16] = acc[mi][ni][r] + bv[ni];
      }
    }
  }
#undef BAR
#undef SBAR
}

extern "C" void kernel_launch(void* const* d_in, const int* in_sizes, int n_in,
                              void* d_out, int out_size, void* d_ws, size_t ws_size,
                              hipStream_t stream) {
  const float* x = (const float*)d_in[0];   // (8,32,1024,256) fp32
  const float* W = (const float*)d_in[1];   // (3,256,256) fp32
  const float* b = (const float*)d_in[2];   // (256,) fp32
  float* y = (float*)d_out;                 // (8,32,1022,256) fp32
  unsigned short* Wt = (unsigned short*)d_ws;  // 3*256*256*2 = 393,216 B

  wprep<<<768, 256, 0, stream>>>(W, Wt);
  conv_mfma<<<NIMG * 8, 512, 0, stream>>>(x, Wt, b, y);
}